// Round 4
// baseline (145.610 us; speedup 1.0000x reference)
//
#include <hip/hip_runtime.h>
#include <hip/hip_bf16.h>

#define NB 8192   // batch
#define ND 512    // feature dim
#define NC 512    // num classes
#define MARGIN_F 1.0f
#define BIGF 3.0e38f
#define BSTRIDE 520   // shorts per LDS B-row (512 + 8 pad)

typedef __attribute__((ext_vector_type(8))) short          bf16x8;
typedef __attribute__((ext_vector_type(8))) unsigned short ushort8;
typedef __attribute__((ext_vector_type(4))) float          f32x4;

__device__ __forceinline__ unsigned fkey(float f) {
    unsigned u = __float_as_uint(f);
    unsigned mask = (u & 0x80000000u) ? 0xFFFFFFFFu : 0x80000000u;
    return u ^ mask;
}
__device__ __forceinline__ float finv(unsigned k) {
    unsigned mask = (k & 0x80000000u) ? 0x80000000u : 0xFFFFFFFFu;
    return __uint_as_float(k ^ mask);
}
__device__ __forceinline__ unsigned short f2bf(float f) {
    __hip_bfloat16 h = __float2bfloat16(f);
    return __builtin_bit_cast(unsigned short, h);
}

// -------------------------------------------------------------------------
// k0: centers fp32->bf16 + csq (blocks 0..127), histogram + done init (128).
// -------------------------------------------------------------------------
__global__ __launch_bounds__(256) void k0_prep(
    const float* __restrict__ centers, const int* __restrict__ targets,
    unsigned short* __restrict__ cenB, float* __restrict__ csq,
    unsigned* __restrict__ counts, unsigned* __restrict__ done)
{
    const int bid = blockIdx.x;
    const int tid = threadIdx.x;

    if (bid == 128) {
        __shared__ unsigned hist[NC];
        for (int i = tid; i < NC; i += 256) hist[i] = 0u;
        __syncthreads();
        for (int i = tid; i < NB; i += 256) atomicAdd(&hist[targets[i]], 1u);
        __syncthreads();
        for (int i = tid; i < NC; i += 256) counts[i] = hist[i];
        if (tid == 0) *done = 0u;
        return;
    }

    const int wave = tid >> 6, lane = tid & 63;
    const int c = bid * 4 + wave;
    const float4* row = (const float4*)&centers[(size_t)c * ND];
    float4 v1 = row[lane];
    float4 v2 = row[lane + 64];
    float s = v1.x*v1.x + v1.y*v1.y + v1.z*v1.z + v1.w*v1.w
            + v2.x*v2.x + v2.y*v2.y + v2.z*v2.z + v2.w*v2.w;

    ushort4 o1, o2;
    o1.x = f2bf(v1.x); o1.y = f2bf(v1.y); o1.z = f2bf(v1.z); o1.w = f2bf(v1.w);
    o2.x = f2bf(v2.x); o2.y = f2bf(v2.y); o2.z = f2bf(v2.z); o2.w = f2bf(v2.w);
    unsigned short* dst = cenB + (size_t)c * ND;
    ((ushort4*)dst)[lane]      = o1;
    ((ushort4*)dst)[lane + 64] = o2;

    #pragma unroll
    for (int off = 32; off > 0; off >>= 1) s += __shfl_down(s, off);
    if (lane == 0) csq[c] = s;
}

// -------------------------------------------------------------------------
// k2: B-strip (128 cols x K=512, bf16) resident in LDS; A streamed directly
//     global->VGPR fragments (fp32, converted in-register). NO barriers in
//     the K-loop. 512 threads = 8 waves (2 row-halves x 4 col-quarters).
//     grid = 256 (1-D, rtile = bid&63 -> XCD-local A reuse).
// -------------------------------------------------------------------------
__global__ __launch_bounds__(512) void k2_mfma(
    const float* __restrict__ inputs, const unsigned short* __restrict__ cenB,
    const int* __restrict__ targets, const unsigned* __restrict__ counts,
    const float* __restrict__ csq,
    float* __restrict__ partmin, float* __restrict__ apval,
    float* __restrict__ rsq, unsigned* __restrict__ done,
    float* __restrict__ out)
{
    __shared__ __align__(16) unsigned short Bs[128 * BSTRIDE];  // 133 KB
    __shared__ int      tgtL[128];
    __shared__ float    csqL[128];
    __shared__ unsigned ldsmin[128];
    __shared__ float    red[16];
    __shared__ int      lastFlag;

    const int tid  = threadIdx.x;
    const int w    = tid >> 6;
    const int lane = tid & 63;
    const int wm   = w >> 2;      // 0..1 : 64-row half
    const int wn   = w & 3;       // 0..3 : 32-col quarter
    const int qd   = lane >> 4;   // quad 0..3
    const int ln   = lane & 15;

    const int bid   = blockIdx.x;
    const int rbase = (bid & 63) * 128;   // rtile fastest -> XCD keeps its A rows
    const int cbase = (bid >> 6) * 128;

    if (tid < 128) {
        tgtL[tid]   = targets[rbase + tid];
        const int c = cbase + tid;
        csqL[tid]   = (counts[c] > 0u) ? csq[c] : BIGF;  // empty class never wins
        ldsmin[tid] = 0xFFFFFFFFu;
    }

    // Stage full B strip: wave w stages cols {w, w+8, ...}; 1 KB per col,
    // lane*16B -> fully coalesced.
    #pragma unroll
    for (int c = 0; c < 16; ++c) {
        const int col = w + c * 8;
        const ushort8 v = *(const ushort8*)(cenB + (size_t)(cbase + col) * ND + lane * 8);
        *(ushort8*)&Bs[col * BSTRIDE + lane * 8] = v;
    }
    __syncthreads();   // the only barrier before the epilogue

    const bool do_rsq = ((bid >> 6) == 0) && (wn == 0);

    // A fragment pointers: lane (ln,qd) of wave wm covers
    // row = rbase + wm*64 + i*16 + ln, k = kb + qd*8 .. +8 (two float4s).
    const float* aptr[4];
    #pragma unroll
    for (int i = 0; i < 4; ++i)
        aptr[i] = inputs + (size_t)(rbase + wm * 64 + i * 16 + ln) * ND + qd * 8;

    float4 cur[8], nxt[8];
    #pragma unroll
    for (int i = 0; i < 4; ++i) {
        cur[2*i]   = *(const float4*)(aptr[i] + 0);
        cur[2*i+1] = *(const float4*)(aptr[i] + 4);
    }

    f32x4 acc[4][2] = {};
    float rs[4] = {};

    #pragma unroll
    for (int kbi = 0; kbi < 16; ++kbi) {
        const int kb = kbi * 32;
        if (kbi < 15) {
            #pragma unroll
            for (int i = 0; i < 4; ++i) {
                nxt[2*i]   = *(const float4*)(aptr[i] + kb + 32);
                nxt[2*i+1] = *(const float4*)(aptr[i] + kb + 36);
            }
        }
        bf16x8 b[2];
        #pragma unroll
        for (int j = 0; j < 2; ++j)
            b[j] = *(const bf16x8*)&Bs[(wn * 32 + j * 16 + ln) * BSTRIDE + kb + qd * 8];

        bf16x8 a[4];
        #pragma unroll
        for (int i = 0; i < 4; ++i) {
            const float4 u = cur[2*i], v = cur[2*i+1];
            bf16x8 t;
            t[0]=(short)f2bf(u.x); t[1]=(short)f2bf(u.y);
            t[2]=(short)f2bf(u.z); t[3]=(short)f2bf(u.w);
            t[4]=(short)f2bf(v.x); t[5]=(short)f2bf(v.y);
            t[6]=(short)f2bf(v.z); t[7]=(short)f2bf(v.w);
            a[i] = t;
            if (do_rsq) {
                rs[i] += u.x*u.x + u.y*u.y + u.z*u.z + u.w*u.w
                       + v.x*v.x + v.y*v.y + v.z*v.z + v.w*v.w;
            }
        }
        #pragma unroll
        for (int i = 0; i < 4; ++i)
            #pragma unroll
            for (int j = 0; j < 2; ++j)
                acc[i][j] = __builtin_amdgcn_mfma_f32_16x16x32_bf16(a[i], b[j], acc[i][j], 0, 0, 0);
        #pragma unroll
        for (int p = 0; p < 8; ++p) cur[p] = nxt[p];
    }

    // row sqnorms: lanes ln, ln+16, ln+32, ln+48 hold the same row's partials
    if (do_rsq) {
        #pragma unroll
        for (int i = 0; i < 4; ++i) {
            float r = rs[i];
            r += __shfl_xor(r, 16);
            r += __shfl_xor(r, 32);
            if (lane < 16) rsq[rbase + wm * 64 + i * 16 + lane] = r;
        }
    }

    // Epilogue. C/D layout: col = lane&15, row = (lane>>4)*4 + reg.
    #pragma unroll
    for (int i = 0; i < 4; ++i) {
        #pragma unroll
        for (int r = 0; r < 4; ++r) {
            const int rlocal = wm * 64 + i * 16 + qd * 4 + r;
            const int grow   = rbase + rlocal;
            const int tr     = tgtL[rlocal];
            float m = BIGF;
            #pragma unroll
            for (int j = 0; j < 2; ++j) {
                const int clocal = wn * 32 + j * 16 + ln;
                const float val = csqL[clocal] - 2.0f * acc[i][j][r];
                if (cbase + clocal == tr) {
                    apval[grow] = val;                 // exactly one writer per row
                } else {
                    m = fminf(m, val);
                }
            }
            #pragma unroll
            for (int off = 1; off < 16; off <<= 1)
                m = fminf(m, __shfl_xor(m, off));
            if (ln == 0) atomicMin(&ldsmin[rlocal], fkey(m));
        }
    }
    __syncthreads();
    if (tid < 128)
        partmin[(size_t)(bid >> 6) * NB + rbase + tid] = finv(ldsmin[tid]);

    // ---- last-done block runs the finalize ----
    __threadfence();
    if (tid == 0) {
        unsigned old = atomicAdd(done, 1u);
        lastFlag = (old == 255u) ? 1 : 0;
    }
    __syncthreads();
    if (!lastFlag) return;
    __threadfence();

    float la = 0.0f, lp = 0.0f;
    for (int rr = tid; rr < NB; rr += 512) {
        float m = fminf(fminf(partmin[rr],        partmin[NB + rr]),
                        fminf(partmin[2*NB + rr], partmin[3*NB + rr]));
        float s  = rsq[rr];
        float an = sqrtf(fmaxf(s + m,         1e-12f));
        float ap = sqrtf(fmaxf(s + apval[rr], 1e-12f));
        la += fmaxf(0.0f, ap - an + MARGIN_F);
        lp += (an > ap) ? 1.0f : 0.0f;
    }
    #pragma unroll
    for (int off = 32; off > 0; off >>= 1) {
        la += __shfl_down(la, off);
        lp += __shfl_down(lp, off);
    }
    if (lane == 0) { red[w] = la; red[8 + w] = lp; }
    __syncthreads();
    if (tid == 0) {
        float A = 0.0f, P = 0.0f;
        #pragma unroll
        for (int i = 0; i < 8; ++i) { A += red[i]; P += red[8 + i]; }
        out[0] = A / (float)NB;
        out[1] = P / (float)NB;
    }
}

extern "C" void kernel_launch(void* const* d_in, const int* in_sizes, int n_in,
                              void* d_out, int out_size, void* d_ws, size_t ws_size,
                              hipStream_t stream) {
    const float* inputs  = (const float*)d_in[0];
    const int*   targets = (const int*)d_in[1];
    const float* centers = (const float*)d_in[2];
    float* out = (float*)d_out;

    // ws layout (bytes):
    char* wp = (char*)d_ws;
    unsigned short* cenB    = (unsigned short*)(wp);            // 512*512*2 = 524288
    float*          csqv    = (float*)(wp + 524288);            // 512*4
    unsigned*       counts  = (unsigned*)(wp + 526336);         // 512*4
    float*          rsq     = (float*)(wp + 528384);            // 8192*4
    float*          apval   = (float*)(wp + 561152);            // 8192*4
    float*          partmin = (float*)(wp + 593920);            // 4*8192*4 = 131072
    unsigned*       done    = (unsigned*)(wp + 724992);         // 4

    k0_prep<<<129, 256, 0, stream>>>(centers, targets, cenB, csqv, counts, done);
    k2_mfma<<<256, 512, 0, stream>>>(inputs, cenB, targets, counts, csqv,
                                     partmin, apval, rsq, done, out);
}

// Round 5
// 129.247 us; speedup vs baseline: 1.1266x; 1.1266x over previous
//
#include <hip/hip_runtime.h>
#include <hip/hip_bf16.h>

#define NB 8192   // batch
#define ND 512    // feature dim
#define NC 512    // num classes
#define MARGIN_F 1.0f
#define BIGF 3.0e38f

typedef __attribute__((ext_vector_type(8))) short          bf16x8;
typedef __attribute__((ext_vector_type(4))) float          f32x4;

__device__ __forceinline__ unsigned fkey(float f) {
    unsigned u = __float_as_uint(f);
    unsigned mask = (u & 0x80000000u) ? 0xFFFFFFFFu : 0x80000000u;
    return u ^ mask;
}
__device__ __forceinline__ float finv(unsigned k) {
    unsigned mask = (k & 0x80000000u) ? 0x80000000u : 0xFFFFFFFFu;
    return __uint_as_float(k ^ mask);
}
__device__ __forceinline__ unsigned short f2bf(float f) {
    __hip_bfloat16 h = __float2bfloat16(f);
    return __builtin_bit_cast(unsigned short, h);
}

#define GLOAD_LDS16(g, l)                                                    \
    __builtin_amdgcn_global_load_lds(                                        \
        (const __attribute__((address_space(1))) void*)(g),                  \
        (__attribute__((address_space(3))) void*)(l), 16, 0, 0)

// -------------------------------------------------------------------------
// k0: fp32->bf16 convert (inputs + centers), row/center sqnorms, negmin
//     init, class histogram + done init. grid = 2177 x 256.
//     Blocks [0,2048): inputs (4 rows each), [2048,2176): centers,
//     block 2176: histogram + done.
// -------------------------------------------------------------------------
__global__ __launch_bounds__(256) void k0_prep(
    const float* __restrict__ inputs, const int* __restrict__ targets,
    const float* __restrict__ centers,
    unsigned short* __restrict__ inB, unsigned short* __restrict__ cenB,
    float* __restrict__ rsq, float* __restrict__ csq,
    unsigned* __restrict__ counts, unsigned* __restrict__ negmin,
    unsigned* __restrict__ done)
{
    const int bid = blockIdx.x;
    const int tid = threadIdx.x;

    if (bid == 2176) {
        __shared__ unsigned hist[NC];
        for (int i = tid; i < NC; i += 256) hist[i] = 0u;
        __syncthreads();
        for (int i = tid; i < NB; i += 256) atomicAdd(&hist[targets[i]], 1u);
        __syncthreads();
        for (int i = tid; i < NC; i += 256) counts[i] = hist[i];
        if (tid == 0) *done = 0u;
        return;
    }

    const int wave = tid >> 6, lane = tid & 63;
    const float* src;
    unsigned short* dst;
    float* sqdst;
    int row;
    bool is_input = (bid < 2048);
    if (is_input) {
        row   = bid * 4 + wave;
        src   = inputs + (size_t)row * ND;
        dst   = inB + (size_t)row * ND;
        sqdst = rsq + row;
    } else {
        row   = (bid - 2048) * 4 + wave;
        src   = centers + (size_t)row * ND;
        dst   = cenB + (size_t)row * ND;
        sqdst = csq + row;
    }

    float4 v1 = ((const float4*)src)[lane];
    float4 v2 = ((const float4*)src)[lane + 64];
    float s = v1.x*v1.x + v1.y*v1.y + v1.z*v1.z + v1.w*v1.w
            + v2.x*v2.x + v2.y*v2.y + v2.z*v2.z + v2.w*v2.w;

    ushort4 o1, o2;
    o1.x = f2bf(v1.x); o1.y = f2bf(v1.y); o1.z = f2bf(v1.z); o1.w = f2bf(v1.w);
    o2.x = f2bf(v2.x); o2.y = f2bf(v2.y); o2.z = f2bf(v2.z); o2.w = f2bf(v2.w);
    ((ushort4*)dst)[lane]      = o1;
    ((ushort4*)dst)[lane + 64] = o2;

    #pragma unroll
    for (int off = 32; off > 0; off >>= 1) s += __shfl_down(s, off);
    if (lane == 0) {
        *sqdst = s;
        if (is_input) negmin[row] = 0xFFFFFFFFu;
    }
}

// -------------------------------------------------------------------------
// k2: bf16 MFMA GEMM + masked-min epilogue + last-block finalize.
// BM=128, BN=64, BK=32, 256 threads = 4 waves (2 row-halves x 2 col-halves,
// wave tile 64x32). grid = 512 blocks (rtile = bid&63 -> XCD-local A reuse),
// 2 blocks/CU so barrier drains overlap across blocks (m97-pattern K-loop).
// -------------------------------------------------------------------------
__global__ __launch_bounds__(256) void k2_mfma(
    const unsigned short* __restrict__ Ain, const unsigned short* __restrict__ cenB,
    const int* __restrict__ targets, const unsigned* __restrict__ counts,
    const float* __restrict__ csq,
    unsigned* __restrict__ negmin, float* __restrict__ apval,
    const float* __restrict__ rsq, unsigned* __restrict__ done,
    float* __restrict__ out)
{
    __shared__ __align__(16) unsigned short As[128 * 32];  // no pad: global_load_lds layout
    __shared__ __align__(16) unsigned short Bs[64 * 32];
    __shared__ int      tgtL[128];
    __shared__ float    csqL[64];
    __shared__ unsigned ldsmin[128];
    __shared__ float    red[8];
    __shared__ int      lastFlag;

    const int tid  = threadIdx.x;
    const int w    = tid >> 6;
    const int lane = tid & 63;
    const int wm   = w >> 1;      // 0..1 : 64-row half
    const int wn   = w & 1;       // 0..1 : 32-col half
    const int qd   = lane >> 4;   // quad 0..3
    const int ln   = lane & 15;

    const int bid   = blockIdx.x;
    const int rbase = (bid & 63) * 128;
    const int cbase = (bid >> 6) * 64;

    if (tid < 128) { tgtL[tid] = targets[rbase + tid]; ldsmin[tid] = 0xFFFFFFFFu; }
    if (tid < 64) {
        const int c = cbase + tid;
        csqL[tid] = (counts[c] > 0u) ? csq[c] : BIGF;   // empty class never wins min
    }

    // Staging map (wave-uniform LDS base + lane*16B, m97 pattern):
    // A: wave w stages rows [w*32, w*32+32) in two 16-row chunks.
    // B: wave w stages rows [w*16, w*16+16).
    const int arow0 = w * 32 + (lane >> 2);
    const int brow  = w * 16 + (lane >> 2);
    const int scol  = (lane & 3) * 8;
    const unsigned short* gA0 = Ain  + (size_t)(rbase + arow0)      * ND + scol;
    const unsigned short* gA1 = Ain  + (size_t)(rbase + arow0 + 16) * ND + scol;
    const unsigned short* gB  = cenB + (size_t)(cbase + brow)       * ND + scol;
    unsigned short* lA0 = &As[(w * 32)      * 32];
    unsigned short* lA1 = &As[(w * 32 + 16) * 32];
    unsigned short* lB  = &Bs[(w * 16)      * 32];

    f32x4 acc[4][2] = {};   // 4 row-frags x 2 col-frags of 16x16

    for (int kb = 0; kb < ND; kb += 32) {
        __syncthreads();                       // prev iter's ds_reads done
        GLOAD_LDS16(gA0 + kb, lA0);
        GLOAD_LDS16(gA1 + kb, lA1);
        GLOAD_LDS16(gB  + kb, lB);
        __syncthreads();                       // drains vmcnt -> tile visible

        bf16x8 a[4], b[2];
        #pragma unroll
        for (int i = 0; i < 4; ++i)
            a[i] = *(const bf16x8*)&As[(wm * 64 + i * 16 + ln) * 32 + qd * 8];
        #pragma unroll
        for (int j = 0; j < 2; ++j)
            b[j] = *(const bf16x8*)&Bs[(wn * 32 + j * 16 + ln) * 32 + qd * 8];
        #pragma unroll
        for (int i = 0; i < 4; ++i)
            #pragma unroll
            for (int j = 0; j < 2; ++j)
                acc[i][j] = __builtin_amdgcn_mfma_f32_16x16x32_bf16(a[i], b[j], acc[i][j], 0, 0, 0);
    }

    // Epilogue. C/D layout: col = lane&15, row = (lane>>4)*4 + reg.
    #pragma unroll
    for (int i = 0; i < 4; ++i) {
        #pragma unroll
        for (int r = 0; r < 4; ++r) {
            const int rlocal = wm * 64 + i * 16 + qd * 4 + r;
            const int grow   = rbase + rlocal;
            const int tr     = tgtL[rlocal];
            float m = BIGF;
            #pragma unroll
            for (int j = 0; j < 2; ++j) {
                const int clocal = wn * 32 + j * 16 + ln;
                const float val = csqL[clocal] - 2.0f * acc[i][j][r];
                if (cbase + clocal == tr) {
                    apval[grow] = val;                 // exactly one writer per row
                } else {
                    m = fminf(m, val);
                }
            }
            #pragma unroll
            for (int off = 1; off < 16; off <<= 1)     // min over 16 cols in-wave
                m = fminf(m, __shfl_xor(m, off));
            if (ln == 0) atomicMin(&ldsmin[rlocal], fkey(m));
        }
    }
    __syncthreads();
    if (tid < 128) {
        unsigned v = ldsmin[tid];
        if (v != 0xFFFFFFFFu) atomicMin(&negmin[rbase + tid], v);
    }

    // ---- last-done block runs the finalize ----
    __threadfence();
    if (tid == 0) {
        unsigned old = atomicAdd(done, 1u);
        lastFlag = (old == 511u) ? 1 : 0;
    }
    __syncthreads();
    if (!lastFlag) return;
    __threadfence();

    float la = 0.0f, lp = 0.0f;
    for (int rr = tid; rr < NB; rr += 256) {
        float s  = rsq[rr];
        float an = sqrtf(fmaxf(s + finv(negmin[rr]), 1e-12f));
        float ap = sqrtf(fmaxf(s + apval[rr],        1e-12f));
        la += fmaxf(0.0f, ap - an + MARGIN_F);
        lp += (an > ap) ? 1.0f : 0.0f;
    }
    #pragma unroll
    for (int off = 32; off > 0; off >>= 1) {
        la += __shfl_down(la, off);
        lp += __shfl_down(lp, off);
    }
    if (lane == 0) { red[w] = la; red[4 + w] = lp; }
    __syncthreads();
    if (tid == 0) {
        float A = 0.0f, P = 0.0f;
        #pragma unroll
        for (int i = 0; i < 4; ++i) { A += red[i]; P += red[4 + i]; }
        out[0] = A / (float)NB;
        out[1] = P / (float)NB;
    }
}

extern "C" void kernel_launch(void* const* d_in, const int* in_sizes, int n_in,
                              void* d_out, int out_size, void* d_ws, size_t ws_size,
                              hipStream_t stream) {
    const float* inputs  = (const float*)d_in[0];
    const int*   targets = (const int*)d_in[1];
    const float* centers = (const float*)d_in[2];
    float* out = (float*)d_out;

    // ws layout (bytes):
    char* wp = (char*)d_ws;
    unsigned short* inB    = (unsigned short*)(wp);             // 8192*512*2 = 8388608
    unsigned short* cenB   = (unsigned short*)(wp + 8388608);   // 512*512*2  = 524288
    float*          rsq    = (float*)(wp + 8912896);            // 8192*4
    float*          csqv   = (float*)(wp + 8945664);            // 512*4
    unsigned*       counts = (unsigned*)(wp + 8947712);         // 512*4
    unsigned*       negmin = (unsigned*)(wp + 8949760);         // 8192*4
    float*          apval  = (float*)(wp + 8982528);            // 8192*4
    unsigned*       done   = (unsigned*)(wp + 9015296);         // 4

    k0_prep<<<2177, 256, 0, stream>>>(inputs, targets, centers,
                                      inB, cenB, rsq, csqv, counts, negmin, done);
    k2_mfma<<<512, 256, 0, stream>>>(inB, cenB, targets, counts, csqv,
                                     negmin, apval, rsq, done, out);
}